// Round 2
// baseline (274.132 us; speedup 1.0000x reference)
//
#include <hip/hip_runtime.h>

// Problem constants (fixed by the reference).
constexpr int N_NODES = 100000;
constexpr int N_EDGES = 1600000;
constexpr int IN_C  = 128;
constexpr int HID_C = 64;   // == OUT_C
constexpr int NUM_CLASSES = 40;

// Bucketed CSR build: 512-node buckets, fixed-capacity staging.
constexpr int BSH = 9;
constexpr int BUCK_N = 1 << BSH;                          // 512
constexpr int NBUCK = (N_NODES + BUCK_N - 1) >> BSH;      // 196
constexpr int BCAP = 9216;      // per-bucket cap; mean 8192, sd~90 (11σ margin)
constexpr int FS_EPT = 16;
constexpr int FS_T = 256;
constexpr int FS_CHUNK = FS_EPT * FS_T;                   // 4096
constexpr int FS_BLKS = (N_EDGES + FS_CHUNK - 1) / FS_CHUNK;  // 391

typedef __attribute__((ext_vector_type(8))) short bf16x8;
typedef __attribute__((ext_vector_type(4))) short short4v;
typedef __attribute__((ext_vector_type(4))) float f32x4;

// bf16 storage helpers (fp32 math everywhere; bf16 only at rest).
__device__ __forceinline__ unsigned short f2bf(float f) {
    unsigned u = __float_as_uint(f);
    return (unsigned short)((u + 0x7FFFu + ((u >> 16) & 1u)) >> 16);   // RNE
}
__device__ __forceinline__ float bf2f(unsigned short h) {
    return __uint_as_float((unsigned)h << 16);
}

// ---------------------------------------------------------------- CSR -------
__global__ void bucket_init_kernel(unsigned* __restrict__ gcur) {
    if (threadIdx.x < NBUCK) gcur[threadIdx.x] = 0u;
}

// Group edges into fixed per-bucket staging regions, packed (src<<9)|dst_lo.
__global__ __launch_bounds__(FS_T) void fill_stage_kernel(
        const int* __restrict__ src, const int* __restrict__ dst,
        unsigned* __restrict__ gcur, unsigned* __restrict__ stage) {
    __shared__ unsigned hist[NBUCK];
    __shared__ unsigned rbase[NBUCK];
    int t = threadIdx.x;
    for (int i = t; i < NBUCK; i += FS_T) hist[i] = 0u;
    __syncthreads();
    int e0 = blockIdx.x * FS_CHUNK + t;
    unsigned pay[FS_EPT];
    unsigned br[FS_EPT];   // (bucket<<16)|rank
#pragma unroll
    for (int i = 0; i < FS_EPT; ++i) {
        int e = e0 + i * FS_T;
        br[i] = 0xFFFFFFFFu; pay[i] = 0u;
        if (e < N_EDGES) {
            unsigned d = (unsigned)dst[e];
            unsigned s = (unsigned)src[e];
            unsigned b = d >> BSH;
            unsigned r = atomicAdd(&hist[b], 1u);   // rank < 4096
            pay[i] = (s << BSH) | (d & (BUCK_N - 1u));
            br[i]  = (b << 16) | r;
        }
    }
    __syncthreads();
    for (int i = t; i < NBUCK; i += FS_T) {
        unsigned c = hist[i];
        rbase[i] = c ? ((unsigned)i * BCAP + atomicAdd(&gcur[i], c)) : 0u;
    }
    __syncthreads();
#pragma unroll
    for (int i = 0; i < FS_EPT; ++i) {
        if (br[i] != 0xFFFFFFFFu) {
            unsigned bb = br[i] >> 16;
            unsigned idx = rbase[bb] + (br[i] & 0xFFFFu);
            if (idx < (bb + 1u) * BCAP) stage[idx] = pay[i];   // safety clamp
        }
    }
}

// Exclusive scan of 196 bucket counts -> bucket bases; total -> rowptr[N].
__global__ __launch_bounds__(256) void scan_buckets_kernel(
        const unsigned* __restrict__ gcur, unsigned* __restrict__ bbase,
        unsigned* __restrict__ rowptr) {
    __shared__ unsigned s[256];
    int t = threadIdx.x;
    unsigned v = (t < NBUCK) ? gcur[t] : 0u;
    s[t] = v;
    __syncthreads();
    for (int off = 1; off < 256; off <<= 1) {
        unsigned u = (t >= off) ? s[t - off] : 0u;
        __syncthreads();
        s[t] += u;
        __syncthreads();
    }
    if (t < NBUCK) bbase[t] = s[t] - v;
    if (t == 255) rowptr[N_NODES] = s[255];
}

// One block per bucket; 512 threads (R11: was 256 — these 196 blocks are
// latency-bound, so 8 waves/block for hiding). Histogram + scan in LDS;
// writes rowptr/inv coalesced; assembles csr slice in LDS; copies out.
__global__ __launch_bounds__(512) void fill_final_kernel(
        const unsigned* __restrict__ gcur, const unsigned* __restrict__ bbase,
        const unsigned* __restrict__ stage, unsigned* __restrict__ rowptr,
        float* __restrict__ inv, unsigned* __restrict__ csr_src) {
    __shared__ unsigned cur[BUCK_N];
    __shared__ unsigned ps[512];
    __shared__ unsigned buf[BCAP];
    int b = blockIdx.x, t = threadIdx.x;
    int lo = b << BSH;
    int nn = min(BUCK_N, N_NODES - lo);
    unsigned c = min(gcur[b], (unsigned)BCAP);
    unsigned base = bbase[b];
    const unsigned* st = stage + (size_t)b * BCAP;
    cur[t] = 0u;
    __syncthreads();
    for (int i = t; i < (int)c; i += 512) atomicAdd(&cur[st[i] & (BUCK_N - 1u)], 1u);
    __syncthreads();
    unsigned d = cur[t];
    ps[t] = d;
    __syncthreads();
    for (int off = 1; off < 512; off <<= 1) {
        unsigned u = (t >= off) ? ps[t - off] : 0u;
        __syncthreads();
        ps[t] += u;
        __syncthreads();
    }
    unsigned off0 = ps[t] - d;   // exclusive prefix
    if (t < nn) {
        rowptr[lo + t] = base + off0;
        inv[lo + t] = rsqrtf((float)(d + 1u));
    }
    __syncthreads();
    cur[t] = off0;
    __syncthreads();
    for (int i = t; i < (int)c; i += 512) {
        unsigned v = st[i];
        unsigned pos = atomicAdd(&cur[v & (BUCK_N - 1u)], 1u);
        buf[pos] = v >> BSH;
    }
    __syncthreads();
    for (int i = t; i < (int)c; i += 512) csr_src[base + i] = buf[i];
}

// ------------------------------------------- MFMA GEMM (X@W)*inv -> bf16 ----
// LDS: Asd[node][k] (k-contiguous, +8 pad -> 2-way-only conflicts),
//      Bsd[outch][k] = W^T (so B-frag is one ds_read_b128).
// Verified layouts (cdna_hip_programming §3): A[m=lane&15][k=quad*8+j],
// B[k=quad*8+j][n=lane&15], D: col=lane&15, row=quad*4+reg.
template <int K, bool BF>
__global__ __launch_bounds__(256) void gemm_mfma_kernel(
        const void* __restrict__ Xv, const float* __restrict__ W,
        const float* __restrict__ inv, unsigned short* __restrict__ out, int n) {
    __shared__ __align__(16) short Asd[64][K + 8];
    __shared__ __align__(16) short Bsd[64][K + 8];
    int t = threadIdx.x;
    int n0 = blockIdx.x * 64;
    // --- stage X -> Asd (node-major, k-contiguous bf16)
    if (BF) {
        const uint4* Xb = (const uint4*)Xv;   // bf16 row = 8 uint4
        for (int i = t; i < 64 * (K / 8); i += 256) {
            int row = i / (K / 8), seg = i % (K / 8);
            int node = n0 + row;
            uint4 v = {0, 0, 0, 0};
            if (node < n) v = Xb[(size_t)node * (K / 8) + seg];
            *(uint4*)&Asd[row][seg * 8] = v;
        }
    } else {
        const float* Xf = (const float*)Xv;
        for (int i = t; i < 64 * (K / 4); i += 256) {
            int row = i / (K / 4), seg = i % (K / 4);
            int node = n0 + row;
            float4 v = {0, 0, 0, 0};
            if (node < n) v = *(const float4*)&Xf[(size_t)node * K + seg * 4];
            short4v o;
            o.x = (short)f2bf(v.x); o.y = (short)f2bf(v.y);
            o.z = (short)f2bf(v.z); o.w = (short)f2bf(v.w);
            *(short4v*)&Asd[row][seg * 4] = o;
        }
    }
    // --- stage W^T -> Bsd (outch-major, k-contiguous bf16)
    for (int i = t; i < K * 16; i += 256) {
        int k = i >> 4, ng = i & 15;
        float4 v = *(const float4*)&W[(size_t)k * 64 + ng * 4];
        Bsd[ng * 4 + 0][k] = (short)f2bf(v.x);
        Bsd[ng * 4 + 1][k] = (short)f2bf(v.y);
        Bsd[ng * 4 + 2][k] = (short)f2bf(v.z);
        Bsd[ng * 4 + 3][k] = (short)f2bf(v.w);
    }
    __syncthreads();
    int wv = t >> 6, lane = t & 63;
    int m = lane & 15, quad = lane >> 4;
    int rowbase = wv * 16;
    f32x4 acc0 = {0,0,0,0}, acc1 = {0,0,0,0}, acc2 = {0,0,0,0}, acc3 = {0,0,0,0};
#pragma unroll
    for (int kb = 0; kb < K / 32; ++kb) {
        bf16x8 af = *(const bf16x8*)&Asd[rowbase + m][kb * 32 + quad * 8];
        bf16x8 b0 = *(const bf16x8*)&Bsd[ 0 + m][kb * 32 + quad * 8];
        bf16x8 b1 = *(const bf16x8*)&Bsd[16 + m][kb * 32 + quad * 8];
        bf16x8 b2 = *(const bf16x8*)&Bsd[32 + m][kb * 32 + quad * 8];
        bf16x8 b3 = *(const bf16x8*)&Bsd[48 + m][kb * 32 + quad * 8];
        acc0 = __builtin_amdgcn_mfma_f32_16x16x32_bf16(af, b0, acc0, 0, 0, 0);
        acc1 = __builtin_amdgcn_mfma_f32_16x16x32_bf16(af, b1, acc1, 0, 0, 0);
        acc2 = __builtin_amdgcn_mfma_f32_16x16x32_bf16(af, b2, acc2, 0, 0, 0);
        acc3 = __builtin_amdgcn_mfma_f32_16x16x32_bf16(af, b3, acc3, 0, 0, 0);
    }
    f32x4 accs[4] = {acc0, acc1, acc2, acc3};
#pragma unroll
    for (int r = 0; r < 4; ++r) {
        int node = n0 + rowbase + quad * 4 + r;
        if (node < n) {
            float sc = inv[node];
#pragma unroll
            for (int s = 0; s < 4; ++s)
                out[(size_t)node * 64 + s * 16 + m] = f2bf(accs[s][r] * sc);
        }
    }
}

// ---------------------------------------- fused gather-aggregate + epilogue -
// One wave per node; one coalesced csr load feeds 64 gathers via __shfl.
// 8 octets x 8 lanes; lane covers 8 channels (one uint4 = 8 bf16).
// GOTCHA (R8): __shfl = ds_bpermute only carries exec-ACTIVE source lanes ->
// loop bound must be wave-uniform (it8); gather predicated on i < navail.
__global__ __launch_bounds__(256) void agg_fused_kernel(
        const unsigned* __restrict__ rowptr, const unsigned* __restrict__ csr_src,
        const unsigned short* __restrict__ hs, const float* __restrict__ inv,
        const float* __restrict__ bias, unsigned short* __restrict__ out) {
    int node = blockIdx.x * 4 + (threadIdx.x >> 6);
    int lane = threadIdx.x & 63;
    int oct = lane >> 3;      // edge slot 0..7
    int cl  = lane & 7;       // channels cl*8 .. cl*8+7
    unsigned beg = rowptr[node], end = rowptr[node + 1];
    float a0 = 0.f, a1 = 0.f, a2 = 0.f, a3 = 0.f;
    float a4 = 0.f, a5 = 0.f, a6 = 0.f, a7 = 0.f;
    const uint4* hsrow = (const uint4*)hs;   // 16 B = 8 bf16; row = 8 uint4
    for (unsigned base = beg; base < end; base += 64) {
        int navail = min((int)(end - base), 64);
        unsigned myidx = 0;
        if (lane < navail) myidx = csr_src[base + lane];
        int it8 = (navail + 7) & ~7;   // wave-uniform trip count
        for (int i = oct; i < it8; i += 8) {
            unsigned s = __shfl(myidx, i);   // all 64 lanes active here
            if (i < navail) {
                uint4 v = hsrow[(size_t)s * 8 + cl];
                a0 += __uint_as_float(v.x << 16);
                a1 += __uint_as_float(v.x & 0xFFFF0000u);
                a2 += __uint_as_float(v.y << 16);
                a3 += __uint_as_float(v.y & 0xFFFF0000u);
                a4 += __uint_as_float(v.z << 16);
                a5 += __uint_as_float(v.z & 0xFFFF0000u);
                a6 += __uint_as_float(v.w << 16);
                a7 += __uint_as_float(v.w & 0xFFFF0000u);
            }
        }
    }
    a0 += __shfl_xor(a0, 8);  a1 += __shfl_xor(a1, 8);
    a2 += __shfl_xor(a2, 8);  a3 += __shfl_xor(a3, 8);
    a4 += __shfl_xor(a4, 8);  a5 += __shfl_xor(a5, 8);
    a6 += __shfl_xor(a6, 8);  a7 += __shfl_xor(a7, 8);
    a0 += __shfl_xor(a0, 16); a1 += __shfl_xor(a1, 16);
    a2 += __shfl_xor(a2, 16); a3 += __shfl_xor(a3, 16);
    a4 += __shfl_xor(a4, 16); a5 += __shfl_xor(a5, 16);
    a6 += __shfl_xor(a6, 16); a7 += __shfl_xor(a7, 16);
    a0 += __shfl_xor(a0, 32); a1 += __shfl_xor(a1, 32);
    a2 += __shfl_xor(a2, 32); a3 += __shfl_xor(a3, 32);
    a4 += __shfl_xor(a4, 32); a5 += __shfl_xor(a5, 32);
    a6 += __shfl_xor(a6, 32); a7 += __shfl_xor(a7, 32);
    if (oct == 0) {
        uint4 sv = hsrow[(size_t)node * 8 + cl];
        float4 bv0 = *(const float4*)&bias[cl * 8];
        float4 bv1 = *(const float4*)&bias[cl * 8 + 4];
        float s = inv[node];
        float r0 = fmaxf(s * (a0 + __uint_as_float(sv.x << 16))        + bv0.x, 0.f);
        float r1 = fmaxf(s * (a1 + __uint_as_float(sv.x & 0xFFFF0000u)) + bv0.y, 0.f);
        float r2 = fmaxf(s * (a2 + __uint_as_float(sv.y << 16))        + bv0.z, 0.f);
        float r3 = fmaxf(s * (a3 + __uint_as_float(sv.y & 0xFFFF0000u)) + bv0.w, 0.f);
        float r4 = fmaxf(s * (a4 + __uint_as_float(sv.z << 16))        + bv1.x, 0.f);
        float r5 = fmaxf(s * (a5 + __uint_as_float(sv.z & 0xFFFF0000u)) + bv1.y, 0.f);
        float r6 = fmaxf(s * (a6 + __uint_as_float(sv.w << 16))        + bv1.z, 0.f);
        float r7 = fmaxf(s * (a7 + __uint_as_float(sv.w & 0xFFFF0000u)) + bv1.w, 0.f);
        uint4 o;
        o.x = (unsigned)f2bf(r0) | ((unsigned)f2bf(r1) << 16);
        o.y = (unsigned)f2bf(r2) | ((unsigned)f2bf(r3) << 16);
        o.z = (unsigned)f2bf(r4) | ((unsigned)f2bf(r5) << 16);
        o.w = (unsigned)f2bf(r6) | ((unsigned)f2bf(r7) << 16);
        ((uint4*)out)[(size_t)node * 8 + cl] = o;
    }
}

// ---------------------------------------------- final classifier GEMM -------
__global__ __launch_bounds__(320) void final_gemm_kernel(
        const unsigned short* __restrict__ H, const float* __restrict__ Wf,
        const float* __restrict__ bfv, float* __restrict__ out, int n) {
    constexpr int CK = 64, J = 40;
    __shared__ float Ws[CK * J];
    __shared__ float Hs[CK][132];
    int t = threadIdx.x;
    int n0 = blockIdx.x * 128;
    for (int i = t; i < CK * J / 4; i += 320)
        ((float4*)Ws)[i] = ((const float4*)Wf)[i];
    for (int i = t; i < 128 * 16; i += 320) {
        int row = i >> 4, kc = i & 15;
        int node = n0 + row;
        ushort4 v = {0, 0, 0, 0};
        if (node < n) v = *(const ushort4*)&H[(size_t)node * 64 + kc * 4];
        Hs[kc * 4 + 0][row] = bf2f(v.x);
        Hs[kc * 4 + 1][row] = bf2f(v.y);
        Hs[kc * 4 + 2][row] = bf2f(v.z);
        Hs[kc * 4 + 3][row] = bf2f(v.w);
    }
    __syncthreads();
    int cg = t % 10;
    int rg = t / 10;
    float4 a0 = {0,0,0,0}, a1 = {0,0,0,0}, a2 = {0,0,0,0}, a3 = {0,0,0,0};
#pragma unroll 8
    for (int k = 0; k < CK; ++k) {
        float4 b = *(const float4*)&Ws[k * J + cg * 4];
        float4 a = *(const float4*)&Hs[k][rg * 4];
        a0.x += a.x * b.x; a0.y += a.x * b.y; a0.z += a.x * b.z; a0.w += a.x * b.w;
        a1.x += a.y * b.x; a1.y += a.y * b.y; a1.z += a.y * b.z; a1.w += a.y * b.w;
        a2.x += a.z * b.x; a2.y += a.z * b.y; a2.z += a.z * b.z; a2.w += a.z * b.w;
        a3.x += a.w * b.x; a3.y += a.w * b.y; a3.z += a.w * b.z; a3.w += a.w * b.w;
    }
    float4 bv = *(const float4*)&bfv[cg * 4];
    float4 accs[4] = {a0, a1, a2, a3};
#pragma unroll
    for (int i = 0; i < 4; ++i) {
        int node = n0 + rg * 4 + i;
        if (node < n) {
            float4 r = accs[i];
            r.x += bv.x; r.y += bv.y; r.z += bv.z; r.w += bv.w;
            *(float4*)&out[(size_t)node * J + cg * 4] = r;
        }
    }
}

// ---------------------------------------------------------------- launch ----
extern "C" void kernel_launch(void* const* d_in, const int* in_sizes, int n_in,
                              void* d_out, int out_size, void* d_ws, size_t ws_size,
                              hipStream_t stream) {
    const float* x  = (const float*)d_in[0];
    const int*   ei = (const int*)d_in[1];
    const float* W1 = (const float*)d_in[2];
    const float* b1 = (const float*)d_in[3];
    const float* W2 = (const float*)d_in[4];
    const float* b2 = (const float*)d_in[5];
    const float* Wf = (const float*)d_in[6];
    const float* bf = (const float*)d_in[7];
    float* out = (float*)d_out;

    const int* src = ei;            // edge_index[0, :]
    const int* dst = ei + N_EDGES;  // edge_index[1, :]

    // Workspace layout (bytes):
    // rowptr: [0, 400064) | inv: [400064, 800064) | gcur: [800064, 800896)
    // bbase: [800896, 801792) | csr_src: [801792, 7201792)
    // A (bf16, 12.8MB): [7201792, 20001792) | B (bf16): [20001792, 32801792)
    // stage (7.23 MB) aliases A: dead before gemm1 writes A (stream-ordered).
    char* ws = (char*)d_ws;
    unsigned* rowptr  = (unsigned*)(ws + 0);
    float*    inv     = (float*)   (ws + 400064);
    unsigned* gcur    = (unsigned*)(ws + 800064);
    unsigned* bbase   = (unsigned*)(ws + 800896);
    unsigned* csr_src = (unsigned*)(ws + 801792);
    unsigned short* A = (unsigned short*)(ws + 7201792);
    unsigned short* B = (unsigned short*)(ws + 20001792);
    unsigned* stage   = (unsigned*)A;

    // ---- CSR build (per-call; no state survives between calls)
    bucket_init_kernel<<<1, 256, 0, stream>>>(gcur);
    fill_stage_kernel<<<FS_BLKS, FS_T, 0, stream>>>(src, dst, gcur, stage);
    scan_buckets_kernel<<<1, 256, 0, stream>>>(gcur, bbase, rowptr);
    fill_final_kernel<<<NBUCK, 512, 0, stream>>>(gcur, bbase, stage, rowptr, inv, csr_src);

    // ---- Layer 1
    gemm_mfma_kernel<IN_C, false>
        <<<(N_NODES + 63) / 64, 256, 0, stream>>>(x, W1, inv, A, N_NODES);
    agg_fused_kernel<<<N_NODES / 4, 256, 0, stream>>>(rowptr, csr_src, A, inv, b1, B);

    // ---- Layer 2
    gemm_mfma_kernel<HID_C, true>
        <<<(N_NODES + 63) / 64, 256, 0, stream>>>(B, W2, inv, A, N_NODES);
    agg_fused_kernel<<<N_NODES / 4, 256, 0, stream>>>(rowptr, csr_src, A, inv, b2, B);

    // ---- Classifier
    final_gemm_kernel<<<(N_NODES + 127) / 128, 320, 0, stream>>>(B, Wf, bf, out, N_NODES);
}

// Round 3
// 244.567 us; speedup vs baseline: 1.1209x; 1.1209x over previous
//
#include <hip/hip_runtime.h>

// Problem constants (fixed by the reference).
constexpr int N_NODES = 100000;
constexpr int N_EDGES = 1600000;
constexpr int IN_C  = 128;
constexpr int HID_C = 64;   // == OUT_C
constexpr int NUM_CLASSES = 40;

// Bucketed CSR build: 512-node buckets, fixed-capacity staging.
constexpr int BSH = 9;
constexpr int BUCK_N = 1 << BSH;                          // 512
constexpr int NBUCK = (N_NODES + BUCK_N - 1) >> BSH;      // 196
constexpr int BCAP = 9216;      // per-bucket cap; mean 8192, sd~90 (11σ margin)
constexpr int FS_EPT = 16;
constexpr int FS_T = 256;
constexpr int FS_CHUNK = FS_EPT * FS_T;                   // 4096
constexpr int FS_BLKS = (N_EDGES + FS_CHUNK - 1) / FS_CHUNK;  // 391

typedef __attribute__((ext_vector_type(8))) short bf16x8;
typedef __attribute__((ext_vector_type(4))) short short4v;
typedef __attribute__((ext_vector_type(4))) float f32x4;

// bf16 storage helpers (fp32 math everywhere; bf16 only at rest).
__device__ __forceinline__ unsigned short f2bf(float f) {
    unsigned u = __float_as_uint(f);
    return (unsigned short)((u + 0x7FFFu + ((u >> 16) & 1u)) >> 16);   // RNE
}
__device__ __forceinline__ float bf2f(unsigned short h) {
    return __uint_as_float((unsigned)h << 16);
}

// ---------------------------------------------------------------- CSR -------
__global__ void bucket_init_kernel(unsigned* __restrict__ gcur) {
    if (threadIdx.x < NBUCK) gcur[threadIdx.x] = 0u;
}

// Group edges into fixed per-bucket staging regions, packed (src<<9)|dst_lo.
__global__ __launch_bounds__(FS_T) void fill_stage_kernel(
        const int* __restrict__ src, const int* __restrict__ dst,
        unsigned* __restrict__ gcur, unsigned* __restrict__ stage) {
    __shared__ unsigned hist[NBUCK];
    __shared__ unsigned rbase[NBUCK];
    int t = threadIdx.x;
    for (int i = t; i < NBUCK; i += FS_T) hist[i] = 0u;
    __syncthreads();
    int e0 = blockIdx.x * FS_CHUNK + t;
    unsigned pay[FS_EPT];
    unsigned br[FS_EPT];   // (bucket<<16)|rank
#pragma unroll
    for (int i = 0; i < FS_EPT; ++i) {
        int e = e0 + i * FS_T;
        br[i] = 0xFFFFFFFFu; pay[i] = 0u;
        if (e < N_EDGES) {
            unsigned d = (unsigned)dst[e];
            unsigned s = (unsigned)src[e];
            unsigned b = d >> BSH;
            unsigned r = atomicAdd(&hist[b], 1u);   // rank < 4096
            pay[i] = (s << BSH) | (d & (BUCK_N - 1u));
            br[i]  = (b << 16) | r;
        }
    }
    __syncthreads();
    for (int i = t; i < NBUCK; i += FS_T) {
        unsigned c = hist[i];
        rbase[i] = c ? ((unsigned)i * BCAP + atomicAdd(&gcur[i], c)) : 0u;
    }
    __syncthreads();
#pragma unroll
    for (int i = 0; i < FS_EPT; ++i) {
        if (br[i] != 0xFFFFFFFFu) {
            unsigned bb = br[i] >> 16;
            unsigned idx = rbase[bb] + (br[i] & 0xFFFFu);
            if (idx < (bb + 1u) * BCAP) stage[idx] = pay[i];   // safety clamp
        }
    }
}

// Exclusive scan of 196 bucket counts -> bucket bases; total -> rowptr[N].
__global__ __launch_bounds__(256) void scan_buckets_kernel(
        const unsigned* __restrict__ gcur, unsigned* __restrict__ bbase,
        unsigned* __restrict__ rowptr) {
    __shared__ unsigned s[256];
    int t = threadIdx.x;
    unsigned v = (t < NBUCK) ? gcur[t] : 0u;
    s[t] = v;
    __syncthreads();
    for (int off = 1; off < 256; off <<= 1) {
        unsigned u = (t >= off) ? s[t - off] : 0u;
        __syncthreads();
        s[t] += u;
        __syncthreads();
    }
    if (t < NBUCK) bbase[t] = s[t] - v;
    if (t == 255) rowptr[N_NODES] = s[255];
}

// One block per bucket; 512 threads. Histogram + scan in LDS;
// writes rowptr/inv coalesced; assembles csr slice in LDS; copies out.
__global__ __launch_bounds__(512) void fill_final_kernel(
        const unsigned* __restrict__ gcur, const unsigned* __restrict__ bbase,
        const unsigned* __restrict__ stage, unsigned* __restrict__ rowptr,
        float* __restrict__ inv, unsigned* __restrict__ csr_src) {
    __shared__ unsigned cur[BUCK_N];
    __shared__ unsigned ps[512];
    __shared__ unsigned buf[BCAP];
    int b = blockIdx.x, t = threadIdx.x;
    int lo = b << BSH;
    int nn = min(BUCK_N, N_NODES - lo);
    unsigned c = min(gcur[b], (unsigned)BCAP);
    unsigned base = bbase[b];
    const unsigned* st = stage + (size_t)b * BCAP;
    cur[t] = 0u;
    __syncthreads();
    for (int i = t; i < (int)c; i += 512) atomicAdd(&cur[st[i] & (BUCK_N - 1u)], 1u);
    __syncthreads();
    unsigned d = cur[t];
    ps[t] = d;
    __syncthreads();
    for (int off = 1; off < 512; off <<= 1) {
        unsigned u = (t >= off) ? ps[t - off] : 0u;
        __syncthreads();
        ps[t] += u;
        __syncthreads();
    }
    unsigned off0 = ps[t] - d;   // exclusive prefix
    if (t < nn) {
        rowptr[lo + t] = base + off0;
        inv[lo + t] = rsqrtf((float)(d + 1u));
    }
    __syncthreads();
    cur[t] = off0;
    __syncthreads();
    for (int i = t; i < (int)c; i += 512) {
        unsigned v = st[i];
        unsigned pos = atomicAdd(&cur[v & (BUCK_N - 1u)], 1u);
        buf[pos] = v >> BSH;
    }
    __syncthreads();
    for (int i = t; i < (int)c; i += 512) csr_src[base + i] = buf[i];
}

// ------------------------------------------- MFMA GEMM (X@W)*inv -> bf16 ----
// LDS: Asd[node][k] (k-contiguous, +8 pad -> 2-way-only conflicts),
//      Bsd[outch][k] = W^T (so B-frag is one ds_read_b128).
// Verified layouts (cdna_hip_programming §3): A[m=lane&15][k=quad*8+j],
// B[k=quad*8+j][n=lane&15], D: col=lane&15, row=quad*4+reg.
template <int K, bool BF>
__global__ __launch_bounds__(256) void gemm_mfma_kernel(
        const void* __restrict__ Xv, const float* __restrict__ W,
        const float* __restrict__ inv, unsigned short* __restrict__ out, int n) {
    __shared__ __align__(16) short Asd[64][K + 8];
    __shared__ __align__(16) short Bsd[64][K + 8];
    int t = threadIdx.x;
    int n0 = blockIdx.x * 64;
    // --- stage X -> Asd (node-major, k-contiguous bf16)
    if (BF) {
        const uint4* Xb = (const uint4*)Xv;   // bf16 row = 8 uint4
        for (int i = t; i < 64 * (K / 8); i += 256) {
            int row = i / (K / 8), seg = i % (K / 8);
            int node = n0 + row;
            uint4 v = {0, 0, 0, 0};
            if (node < n) v = Xb[(size_t)node * (K / 8) + seg];
            *(uint4*)&Asd[row][seg * 8] = v;
        }
    } else {
        const float* Xf = (const float*)Xv;
        for (int i = t; i < 64 * (K / 4); i += 256) {
            int row = i / (K / 4), seg = i % (K / 4);
            int node = n0 + row;
            float4 v = {0, 0, 0, 0};
            if (node < n) v = *(const float4*)&Xf[(size_t)node * K + seg * 4];
            short4v o;
            o.x = (short)f2bf(v.x); o.y = (short)f2bf(v.y);
            o.z = (short)f2bf(v.z); o.w = (short)f2bf(v.w);
            *(short4v*)&Asd[row][seg * 4] = o;
        }
    }
    // --- stage W^T -> Bsd (outch-major, k-contiguous bf16)
    for (int i = t; i < K * 16; i += 256) {
        int k = i >> 4, ng = i & 15;
        float4 v = *(const float4*)&W[(size_t)k * 64 + ng * 4];
        Bsd[ng * 4 + 0][k] = (short)f2bf(v.x);
        Bsd[ng * 4 + 1][k] = (short)f2bf(v.y);
        Bsd[ng * 4 + 2][k] = (short)f2bf(v.z);
        Bsd[ng * 4 + 3][k] = (short)f2bf(v.w);
    }
    __syncthreads();
    int wv = t >> 6, lane = t & 63;
    int m = lane & 15, quad = lane >> 4;
    int rowbase = wv * 16;
    f32x4 acc0 = {0,0,0,0}, acc1 = {0,0,0,0}, acc2 = {0,0,0,0}, acc3 = {0,0,0,0};
#pragma unroll
    for (int kb = 0; kb < K / 32; ++kb) {
        bf16x8 af = *(const bf16x8*)&Asd[rowbase + m][kb * 32 + quad * 8];
        bf16x8 b0 = *(const bf16x8*)&Bsd[ 0 + m][kb * 32 + quad * 8];
        bf16x8 b1 = *(const bf16x8*)&Bsd[16 + m][kb * 32 + quad * 8];
        bf16x8 b2 = *(const bf16x8*)&Bsd[32 + m][kb * 32 + quad * 8];
        bf16x8 b3 = *(const bf16x8*)&Bsd[48 + m][kb * 32 + quad * 8];
        acc0 = __builtin_amdgcn_mfma_f32_16x16x32_bf16(af, b0, acc0, 0, 0, 0);
        acc1 = __builtin_amdgcn_mfma_f32_16x16x32_bf16(af, b1, acc1, 0, 0, 0);
        acc2 = __builtin_amdgcn_mfma_f32_16x16x32_bf16(af, b2, acc2, 0, 0, 0);
        acc3 = __builtin_amdgcn_mfma_f32_16x16x32_bf16(af, b3, acc3, 0, 0, 0);
    }
    f32x4 accs[4] = {acc0, acc1, acc2, acc3};
#pragma unroll
    for (int r = 0; r < 4; ++r) {
        int node = n0 + rowbase + quad * 4 + r;
        if (node < n) {
            float sc = inv[node];
#pragma unroll
            for (int s = 0; s < 4; ++s)
                out[(size_t)node * 64 + s * 16 + m] = f2bf(accs[s][r] * sc);
        }
    }
}

// ---------------------------------------- fused gather-aggregate + epilogue -
// R2 restructure: one node per 8-lane OCTET (8 nodes/wave). Lane permanently
// owns channels cl*8..cl*8+7 (one uint4 = 8 bf16), so there is NO cross-lane
// reduction and NO __shfl index broadcast: each lane walks its node's edge
// list directly (index loads are octet-uniform -> coalesced broadcast; 8
// independent edges in flight per wave iteration, unroll 4 for MLP).
// Removes per-node fixed cost that dominated R2 profile (VALUBusy 58%,
// MfmaUtil 0, hbm 26% -> latency/overhead-bound at 48 us).
__global__ __launch_bounds__(256) void agg_fused_kernel(
        const unsigned* __restrict__ rowptr, const unsigned* __restrict__ csr_src,
        const unsigned short* __restrict__ hs, const float* __restrict__ inv,
        const float* __restrict__ bias, unsigned short* __restrict__ out) {
    int t = threadIdx.x;
    int lane = t & 63;
    int oct = lane >> 3;      // which node of the wave's 8
    int cl  = lane & 7;       // channel group: channels cl*8 .. cl*8+7
    int node = blockIdx.x * 32 + (t >> 6) * 8 + oct;
    unsigned beg = rowptr[node], end = rowptr[node + 1];
    float a0 = 0.f, a1 = 0.f, a2 = 0.f, a3 = 0.f;
    float a4 = 0.f, a5 = 0.f, a6 = 0.f, a7 = 0.f;
    const uint4* hsrow = (const uint4*)hs;   // 16 B = 8 bf16; row = 8 uint4
#pragma unroll 4
    for (unsigned e = beg; e < end; ++e) {
        unsigned s = csr_src[e];             // octet-uniform -> broadcast
        uint4 v = hsrow[(size_t)s * 8 + cl];
        a0 += __uint_as_float(v.x << 16);
        a1 += __uint_as_float(v.x & 0xFFFF0000u);
        a2 += __uint_as_float(v.y << 16);
        a3 += __uint_as_float(v.y & 0xFFFF0000u);
        a4 += __uint_as_float(v.z << 16);
        a5 += __uint_as_float(v.z & 0xFFFF0000u);
        a6 += __uint_as_float(v.w << 16);
        a7 += __uint_as_float(v.w & 0xFFFF0000u);
    }
    // Epilogue: every lane owns its channels; wave stores 1 KB contiguous.
    uint4 sv = hsrow[(size_t)node * 8 + cl];
    float4 bv0 = *(const float4*)&bias[cl * 8];
    float4 bv1 = *(const float4*)&bias[cl * 8 + 4];
    float s = inv[node];
    float r0 = fmaxf(s * (a0 + __uint_as_float(sv.x << 16))         + bv0.x, 0.f);
    float r1 = fmaxf(s * (a1 + __uint_as_float(sv.x & 0xFFFF0000u)) + bv0.y, 0.f);
    float r2 = fmaxf(s * (a2 + __uint_as_float(sv.y << 16))         + bv0.z, 0.f);
    float r3 = fmaxf(s * (a3 + __uint_as_float(sv.y & 0xFFFF0000u)) + bv0.w, 0.f);
    float r4 = fmaxf(s * (a4 + __uint_as_float(sv.z << 16))         + bv1.x, 0.f);
    float r5 = fmaxf(s * (a5 + __uint_as_float(sv.z & 0xFFFF0000u)) + bv1.y, 0.f);
    float r6 = fmaxf(s * (a6 + __uint_as_float(sv.w << 16))         + bv1.z, 0.f);
    float r7 = fmaxf(s * (a7 + __uint_as_float(sv.w & 0xFFFF0000u)) + bv1.w, 0.f);
    uint4 o;
    o.x = (unsigned)f2bf(r0) | ((unsigned)f2bf(r1) << 16);
    o.y = (unsigned)f2bf(r2) | ((unsigned)f2bf(r3) << 16);
    o.z = (unsigned)f2bf(r4) | ((unsigned)f2bf(r5) << 16);
    o.w = (unsigned)f2bf(r6) | ((unsigned)f2bf(r7) << 16);
    ((uint4*)out)[(size_t)node * 8 + cl] = o;
}

// ---------------------------------------------- final classifier GEMM -------
__global__ __launch_bounds__(320) void final_gemm_kernel(
        const unsigned short* __restrict__ H, const float* __restrict__ Wf,
        const float* __restrict__ bfv, float* __restrict__ out, int n) {
    constexpr int CK = 64, J = 40;
    __shared__ float Ws[CK * J];
    __shared__ float Hs[CK][132];
    int t = threadIdx.x;
    int n0 = blockIdx.x * 128;
    for (int i = t; i < CK * J / 4; i += 320)
        ((float4*)Ws)[i] = ((const float4*)Wf)[i];
    for (int i = t; i < 128 * 16; i += 320) {
        int row = i >> 4, kc = i & 15;
        int node = n0 + row;
        ushort4 v = {0, 0, 0, 0};
        if (node < n) v = *(const ushort4*)&H[(size_t)node * 64 + kc * 4];
        Hs[kc * 4 + 0][row] = bf2f(v.x);
        Hs[kc * 4 + 1][row] = bf2f(v.y);
        Hs[kc * 4 + 2][row] = bf2f(v.z);
        Hs[kc * 4 + 3][row] = bf2f(v.w);
    }
    __syncthreads();
    int cg = t % 10;
    int rg = t / 10;
    float4 a0 = {0,0,0,0}, a1 = {0,0,0,0}, a2 = {0,0,0,0}, a3 = {0,0,0,0};
#pragma unroll 8
    for (int k = 0; k < CK; ++k) {
        float4 b = *(const float4*)&Ws[k * J + cg * 4];
        float4 a = *(const float4*)&Hs[k][rg * 4];
        a0.x += a.x * b.x; a0.y += a.x * b.y; a0.z += a.x * b.z; a0.w += a.x * b.w;
        a1.x += a.y * b.x; a1.y += a.y * b.y; a1.z += a.y * b.z; a1.w += a.y * b.w;
        a2.x += a.z * b.x; a2.y += a.z * b.y; a2.z += a.z * b.z; a2.w += a.z * b.w;
        a3.x += a.w * b.x; a3.y += a.w * b.y; a3.z += a.w * b.z; a3.w += a.w * b.w;
    }
    float4 bv = *(const float4*)&bfv[cg * 4];
    float4 accs[4] = {a0, a1, a2, a3};
#pragma unroll
    for (int i = 0; i < 4; ++i) {
        int node = n0 + rg * 4 + i;
        if (node < n) {
            float4 r = accs[i];
            r.x += bv.x; r.y += bv.y; r.z += bv.z; r.w += bv.w;
            *(float4*)&out[(size_t)node * J + cg * 4] = r;
        }
    }
}

// ---------------------------------------------------------------- launch ----
extern "C" void kernel_launch(void* const* d_in, const int* in_sizes, int n_in,
                              void* d_out, int out_size, void* d_ws, size_t ws_size,
                              hipStream_t stream) {
    const float* x  = (const float*)d_in[0];
    const int*   ei = (const int*)d_in[1];
    const float* W1 = (const float*)d_in[2];
    const float* b1 = (const float*)d_in[3];
    const float* W2 = (const float*)d_in[4];
    const float* b2 = (const float*)d_in[5];
    const float* Wf = (const float*)d_in[6];
    const float* bf = (const float*)d_in[7];
    float* out = (float*)d_out;

    const int* src = ei;            // edge_index[0, :]
    const int* dst = ei + N_EDGES;  // edge_index[1, :]

    // Workspace layout (bytes):
    // rowptr: [0, 400064) | inv: [400064, 800064) | gcur: [800064, 800896)
    // bbase: [800896, 801792) | csr_src: [801792, 7201792)
    // A (bf16, 12.8MB): [7201792, 20001792) | B (bf16): [20001792, 32801792)
    // stage (7.23 MB) aliases A: dead before gemm1 writes A (stream-ordered).
    char* ws = (char*)d_ws;
    unsigned* rowptr  = (unsigned*)(ws + 0);
    float*    inv     = (float*)   (ws + 400064);
    unsigned* gcur    = (unsigned*)(ws + 800064);
    unsigned* bbase   = (unsigned*)(ws + 800896);
    unsigned* csr_src = (unsigned*)(ws + 801792);
    unsigned short* A = (unsigned short*)(ws + 7201792);
    unsigned short* B = (unsigned short*)(ws + 20001792);
    unsigned* stage   = (unsigned*)A;

    // ---- CSR build (per-call; no state survives between calls)
    bucket_init_kernel<<<1, 256, 0, stream>>>(gcur);
    fill_stage_kernel<<<FS_BLKS, FS_T, 0, stream>>>(src, dst, gcur, stage);
    scan_buckets_kernel<<<1, 256, 0, stream>>>(gcur, bbase, rowptr);
    fill_final_kernel<<<NBUCK, 512, 0, stream>>>(gcur, bbase, stage, rowptr, inv, csr_src);

    // ---- Layer 1
    gemm_mfma_kernel<IN_C, false>
        <<<(N_NODES + 63) / 64, 256, 0, stream>>>(x, W1, inv, A, N_NODES);
    agg_fused_kernel<<<N_NODES / 32, 256, 0, stream>>>(rowptr, csr_src, A, inv, b1, B);

    // ---- Layer 2
    gemm_mfma_kernel<HID_C, true>
        <<<(N_NODES + 63) / 64, 256, 0, stream>>>(B, W2, inv, A, N_NODES);
    agg_fused_kernel<<<N_NODES / 32, 256, 0, stream>>>(rowptr, csr_src, A, inv, b2, B);

    // ---- Classifier
    final_gemm_kernel<<<(N_NODES + 127) / 128, 320, 0, stream>>>(B, Wf, bf, out, N_NODES);
}